// Round 13
// baseline (79.142 us; speedup 1.0000x reference)
//
#include <hip/hip_runtime.h>
#include <math.h>

#define NQ   11
#define DIM  2048        // 2^11
#define NL   6

typedef float v2f __attribute__((ext_vector_type(2)));   // (re, im)

// GF(2)-linear swizzle for kernel 1 (R3-R10 proven conflict-free)
__host__ __device__ constexpr int swzA(int x) {
    return x ^ ((x >> 6) & 31) ^ ((x & 2) << 3) ^ ((x & 1) << 3);
}
// h = g^{-1} of the CNOT-chain perm g(o)=o^(o>>1): prefix-XOR from MSB
__host__ __device__ constexpr int hperm(int x) {
    return x ^ (x>>1) ^ (x>>2) ^ (x>>3) ^ (x>>4) ^ (x>>5)
             ^ (x>>6) ^ (x>>7) ^ (x>>8) ^ (x>>9) ^ (x>>10);
}

__device__ __forceinline__ float2 cfma2(float2 u, float2 a, float2 v, float2 b) {
    float2 r;
    r.x = u.x*a.x - u.y*a.y + v.x*b.x - v.y*b.y;
    r.y = u.x*a.y + u.y*a.x + v.x*b.y + v.y*b.x;
    return r;
}

// DPP lane-xor (VALU pipe): 177=xor1, 27=xor3, 0x141=xor7, 0x140=xor15
template<int CTRL>
__device__ __forceinline__ v2f dpp_xor(v2f v) {
    const int x = __builtin_amdgcn_update_dpp(
        0, __float_as_int(v.x), CTRL, 0xF, 0xF, true);
    const int y = __builtin_amdgcn_update_dpp(
        0, __float_as_int(v.y), CTRL, 0xF, 0xF, true);
    v2f r; r.x = __int_as_float(x); r.y = __int_as_float(y);
    return r;
}

// ================= kernel 1: all sample-independent work, 1 block ============
// (byte-for-byte the proven R5/R8/R10 version)
__global__ __launch_bounds__(256) void qnn_shared_kernel(
    const float* __restrict__ P,      // (NL, NQ, 3)
    float2* __restrict__ ws)          // out: 2048 float2, natural order
{
    __shared__ float2 lds[DIM];
    __shared__ float2 G[NL*NQ][4];
    const int t = threadIdx.x;        // 8 bits

    if (t < NL*NQ) {
        const float p0 = P[t*3+0], p1 = P[t*3+1], p2 = P[t*3+2];
        const float th = 0.5f*p1;
        const float c  = cosf(th), s = sinf(th);
        const float al = 0.5f*(p0+p2), be = 0.5f*(p0-p2);
        const float ca = cosf(al), sa = sinf(al);
        const float cb = cosf(be), sb = sinf(be);
        G[t][0] = make_float2( c*ca, -c*sa);
        G[t][1] = make_float2(-s*cb, -s*sb);
        G[t][2] = make_float2( s*cb, -s*sb);
        G[t][3] = make_float2( c*ca,  c*sa);
    }

    const int a0w = swzA(t);                          // X1 write (k<<8)
    const int a1b = swzA(((t>>5)<<8) | (t&31));       // X1 read / X2 write (k<<5)
    const int a2b = swzA(((t>>2)<<5) | (t&3));        // X2 read / X3 write (k<<2)
    const int a3b = swzA(t ^ (t>>1));                 // X3 perm-gather read
    const int natb = ((t>>2)<<5) | (t&3);             // ws natural-order base

    float2 a[8];
    #pragma unroll
    for (int k = 0; k < 8; ++k) a[k] = make_float2(0.f, 0.f);
    if (t == 0) a[0] = make_float2(1.f, 0.f);
    __syncthreads();   // G ready

    #define CG(g_, rb_) { \
        const float2 U00=G[g_][0], U01=G[g_][1], U10=G[g_][2], U11=G[g_][3]; \
        _Pragma("unroll") \
        for (int kk = 0; kk < 8; ++kk) if (!(kk & (rb_))) { \
            const float2 a0 = a[kk], a1 = a[kk|(rb_)]; \
            a[kk]       = cfma2(U00, a0, U01, a1); \
            a[kk|(rb_)] = cfma2(U10, a0, U11, a1); \
        } }

    #define SG(g_, m_, b_) { \
        const float2 ca_ = (b_) ? G[g_][3] : G[g_][0]; \
        const float2 cb_ = (b_) ? G[g_][2] : G[g_][1]; \
        _Pragma("unroll") \
        for (int kk = 0; kk < 8; ++kk) { \
            float2 p; \
            p.x = __shfl_xor(a[kk].x, m_); \
            p.y = __shfl_xor(a[kk].y, m_); \
            a[kk] = cfma2(ca_, a[kk], cb_, p); \
        } }

    for (int l = 0; l < NL; ++l) {
        const int g0 = l*NQ;
        CG(g0+0, 4) CG(g0+1, 2) CG(g0+2, 1)          // qubits 0,1,2 (bits 10,9,8)

        #pragma unroll
        for (int k = 0; k < 8; ++k) lds[a0w ^ swzA(k<<8)] = a[k];
        __syncthreads();
        #pragma unroll
        for (int k = 0; k < 8; ++k) a[k] = lds[a1b ^ swzA(k<<5)];
        __syncthreads();
        CG(g0+3, 4) CG(g0+4, 2) CG(g0+5, 1)          // qubits 3,4,5 (bits 7,6,5)

        #pragma unroll
        for (int k = 0; k < 8; ++k) lds[a1b ^ swzA(k<<5)] = a[k];
        __syncthreads();
        #pragma unroll
        for (int k = 0; k < 8; ++k) a[k] = lds[a2b ^ swzA(k<<2)];
        __syncthreads();
        CG(g0+6, 4) CG(g0+7, 2) CG(g0+8, 1)          // qubits 6,7,8 (bits 4,3,2)

        SG(g0+9, 2, (t>>1)&1)                        // qubit 9 (bit 1)
        SG(g0+10, 1, t&1)                            // qubit 10 (bit 0)

        if (l < NL-1) {
            #pragma unroll
            for (int k = 0; k < 8; ++k) lds[a2b ^ swzA(k<<2)] = a[k];
            __syncthreads();
            #pragma unroll
            for (int k = 0; k < 8; ++k)
                a[k] = lds[a3b ^ swzA((k<<8) ^ (k<<7))];   // src = g((k<<8)|t)
            __syncthreads();
        } else {
            #pragma unroll
            for (int k = 0; k < 8; ++k) ws[natb | (k<<2)] = a[k];
        }
    }
    #undef CG
    #undef SG
}

// ========= kernel 2: cell-paired (float4) layout, 8192 blocks ================
// (byte-for-byte the proven R10 version, 52.12 µs total)
__global__ __launch_bounds__(128, 4) void qnn_last_kernel(
    const float* __restrict__ X,      // (B, NQ)
    const float4* __restrict__ S5c,   // shared state, 1024 cells, natural order
    float4* __restrict__ out4)        // (B, 1024) cells
{
    __shared__ float4 ldsc[DIM/2];    // 1024 cells = 16 KB
    __shared__ float2 gc[NQ];
    const int b = blockIdx.x;
    const int t = threadIdx.x;        // 7 bits

    if (t < NQ) {
        const float tx = 0.5f * X[(size_t)b*NQ + t];
        gc[t] = make_float2(cosf(tx), sinf(tx));
    }

    // L0: a[2k+e] = amp s=(k<<8)|(t<<1)|e ; cell (k<<7)|t ; 1KB/wave loads
    v2f a[16];
    #pragma unroll
    for (int k = 0; k < 8; ++k) {
        const float4 v = S5c[(k<<7) | t];
        a[2*k]   = (v2f){v.x, v.y};
        a[2*k+1] = (v2f){v.z, v.w};
    }
    __syncthreads();   // bar1: gc ready

    // packed real RY on a-index bit rb_
    #define RG(q_, rb_) { \
        const float c = gc[q_].x, sn = gc[q_].y; \
        const v2f cc = {c, c}, sv = {sn, sn}; \
        _Pragma("unroll") \
        for (int j = 0; j < 16; ++j) if (!(j & (rb_))) { \
            const v2f a0 = a[j], a1 = a[j|(rb_)]; \
            a[j]       = cc*a0 - sv*a1; \
            a[j|(rb_)] = sv*a0 + cc*a1; \
        } }

    // o-domain conjugated RY: partner = lane-xor (DPP) of e-swapped reg
    #define CGD(q_, CTRL_, r_) { \
        const float c = gc[q_].x, sn = gc[q_].y; \
        const float sg = (r_) ? sn : -sn; \
        const v2f cc = {c, c}, sgv = {sg, sg}; \
        _Pragma("unroll") \
        for (int k = 0; k < 8; ++k) { \
            const v2f o0 = a[2*k], o1 = a[2*k+1]; \
            const v2f p0 = dpp_xor<CTRL_>(o1); \
            const v2f p1 = dpp_xor<CTRL_>(o0); \
            a[2*k]   = cc*o0 + sgv*p0; \
            a[2*k+1] = cc*o1 + sgv*p1; \
        } }

    // S1: reg amp-bits {10,9,8} = k, {0} = e
    RG(0, 8) RG(1, 4) RG(2, 2) RG(10, 1)

    // X1 write: cell (k<<7)|t
    #pragma unroll
    for (int k = 0; k < 8; ++k)
        ldsc[(k<<7) | t] = make_float4(a[2*k].x, a[2*k].y, a[2*k+1].x, a[2*k+1].y);
    __syncthreads();   // bar2
    // X1 read: s = (t[6:4]<<8)|(k<<5)|(t[3:1]<<2)|(t0<<1)|e ; cell = s>>1
    const int cR = ((t>>4)<<7) | (t & 15);
    #pragma unroll
    for (int k = 0; k < 8; ++k) {
        const float4 v = ldsc[cR | (k<<4)];
        a[2*k]   = (v2f){v.x, v.y};
        a[2*k+1] = (v2f){v.z, v.w};
    }
    // S2: reg amp-bits {7,6,5} = k
    RG(3, 8) RG(4, 4) RG(5, 2)
    __syncthreads();   // bar3: all X1 reads done before h-scattered writes

    // X2 write, perm-folded: amp s -> LDS slot h(s), so LDS[o] = V[g(o)].
    {
        const int sB    = (((t>>4)&7)<<8) | (((t>>1)&7)<<2) | ((t&1)<<1);
        const int cellB = hperm(sB) >> 1;
        const int pt    = __popc(t) & 1;
        #pragma unroll
        for (int k = 0; k < 8; ++k) {
            const int cell = cellB ^ (hperm(k<<5) >> 1);   // constexpr k-part
            const bool sw  = (pt ^ (__popc(k) & 1)) != 0;
            const v2f lo = sw ? a[2*k+1] : a[2*k];
            const v2f hi = sw ? a[2*k]   : a[2*k+1];
            ldsc[cell] = make_float4(lo.x, lo.y, hi.x, hi.y);
        }
    }
    __syncthreads();   // bar4

    // X2 read, linear: a[2k+e] = V[g(o)], o = (k<<8)|(t<<1)|e
    #pragma unroll
    for (int k = 0; k < 8; ++k) {
        const float4 v = ldsc[(k<<7) | t];
        a[2*k]   = (v2f){v.x, v.y};
        a[2*k+1] = (v2f){v.z, v.w};
    }

    // S3: q6..q9 conjugated through g -> lane-xor {15,7,3,1} + e-swap
    CGD(6, 0x140, ((t>>3) ^ (t>>4)) & 1)
    CGD(7, 0x141, ((t>>2) ^ (t>>3)) & 1)
    CGD(8, 27,    ((t>>1) ^ (t>>2)) & 1)
    CGD(9, 177,   ( t     ^ (t>>1)) & 1)

    // store: cell (k<<7)|t -> 1KB/wave contiguous bursts
    float4* o = out4 + (size_t)b * (DIM/2);
    #pragma unroll
    for (int k = 0; k < 8; ++k)
        o[(k<<7) | t] = make_float4(a[2*k].x, a[2*k].y, a[2*k+1].x, a[2*k+1].y);
    #undef RG
    #undef CGD
}

extern "C" void kernel_launch(void* const* d_in, const int* in_sizes, int n_in,
                              void* d_out, int out_size, void* d_ws, size_t ws_size,
                              hipStream_t stream) {
    const float* X = (const float*)d_in[0];   // (B, NQ) float32
    const float* P = (const float*)d_in[1];   // (NL, NQ, 3) float32
    float2* ws  = (float2*)d_ws;              // 16 KB shared state (16B-aligned)
    const int B = in_sizes[0] / NQ;           // 8192
    qnn_shared_kernel<<<1, 256, 0, stream>>>(P, ws);
    // MEASUREMENT ROUND: k2 launched twice (idempotent -> identical output).
    // total_R13 - total_R10 = k2 duration; isolates the k1/k2 split that has
    // been invisible under the harness fill dispatches since R2.
    qnn_last_kernel<<<B, 128, 0, stream>>>(X, (const float4*)ws, (float4*)d_out);
    qnn_last_kernel<<<B, 128, 0, stream>>>(X, (const float4*)ws, (float4*)d_out);
}

// Round 14
// 51.894 us; speedup vs baseline: 1.5251x; 1.5251x over previous
//
#include <hip/hip_runtime.h>
#include <math.h>

#define NQ   11
#define DIM  2048        // 2^11
#define NL   6

typedef float v2f __attribute__((ext_vector_type(2)));   // (re, im)

// h = g^{-1} of the CNOT-chain perm g(o)=o^(o>>1): prefix-XOR from MSB
__host__ __device__ constexpr int hperm(int x) {
    return x ^ (x>>1) ^ (x>>2) ^ (x>>3) ^ (x>>4) ^ (x>>5)
             ^ (x>>6) ^ (x>>7) ^ (x>>8) ^ (x>>9) ^ (x>>10);
}

__device__ __forceinline__ float2 cfma2(float2 u, float2 a, float2 v, float2 b) {
    float2 r;
    r.x = u.x*a.x - u.y*a.y + v.x*b.x - v.y*b.y;
    r.y = u.x*a.y + u.y*a.x + v.x*b.y + v.y*b.x;
    return r;
}

// DPP lane-xor (VALU pipe): 177=xor1, 78=xor2, 27=xor3, 0x141=xor7, 0x140=xor15
template<int CTRL>
__device__ __forceinline__ v2f dpp_xor(v2f v) {
    const int x = __builtin_amdgcn_update_dpp(
        0, __float_as_int(v.x), CTRL, 0xF, 0xF, true);
    const int y = __builtin_amdgcn_update_dpp(
        0, __float_as_int(v.y), CTRL, 0xF, 0xF, true);
    v2f r; r.x = __int_as_float(x); r.y = __int_as_float(y);
    return r;
}
template<int CTRL>
__device__ __forceinline__ float2 dpp_xor_f2(float2 v) {
    float2 r;
    r.x = __int_as_float(__builtin_amdgcn_update_dpp(
        0, __float_as_int(v.x), CTRL, 0xF, 0xF, true));
    r.y = __int_as_float(__builtin_amdgcn_update_dpp(
        0, __float_as_int(v.y), CTRL, 0xF, 0xF, true));
    return r;
}

// ============ kernel 1: all sample-independent work, 1 block of 1024 =========
// 16 waves (4/SIMD) x 2 amps/thread -> latency hiding the old 4-wave version
// lacked. Per layer: reg gate q0 + lane gates q5..q10, X1 (amp[9:6]<->t[5:2]),
// lane gates q1..q4, X2 with CNOT-perm fold. swzC keeps every b64 pattern at
// the structural bank floor.
__global__ __launch_bounds__(1024) void qnn_shared_kernel(
    const float* __restrict__ P,      // (NL, NQ, 3)
    float4* __restrict__ ws4)         // out: 1024 cells (amp pairs), natural
{
    __shared__ float2 lds[DIM];
    __shared__ float2 G[NL*NQ][4];
    const int t = threadIdx.x;        // 10 bits

    if (t < NL*NQ) {
        const float p0 = P[t*3+0], p1 = P[t*3+1], p2 = P[t*3+2];
        const float th = 0.5f*p1;
        const float c  = cosf(th), s = sinf(th);
        const float al = 0.5f*(p0+p2), be = 0.5f*(p0-p2);
        const float ca = cosf(al), sa = sinf(al);
        const float cb = cosf(be), sb = sinf(be);
        G[t][0] = make_float2( c*ca, -c*sa);
        G[t][1] = make_float2(-s*cb, -s*sb);
        G[t][2] = make_float2( s*cb, -s*sb);
        G[t][3] = make_float2( c*ca,  c*sa);
    }

    // swzC(a) = a ^ ((a>>6)&15)  (GF(2)-linear, bit10 untouched)
    const int b0 = t ^ ((t >> 6) & 15);                       // X1 write base
    const int lin1 = (((t>>2)&15)<<6) | (((t>>6)&15)<<2) | (t&3);
    const int b1 = lin1 ^ ((t >> 2) & 15);                    // X1 read / X2 write
    const int gt = t ^ (t >> 1);
    const int b2 = gt ^ ((gt >> 6) & 15);                     // X2 perm read (k=0)
    const int bn = (2*t) ^ (((2*t) >> 6) & 15);               // final natural read

    float2 a0 = make_float2(0.f, 0.f), a1 = make_float2(0.f, 0.f);
    if (t == 0) a0 = make_float2(1.f, 0.f);
    __syncthreads();   // G ready

    // complex gate on reg bit k (amp bit 10)
    #define CGK(g_) { \
        const float2 n0 = cfma2(G[g_][0], a0, G[g_][1], a1); \
        const float2 n1 = cfma2(G[g_][2], a0, G[g_][3], a1); \
        a0 = n0; a1 = n1; }

    // complex gate on lane bit (mask m_), via shfl; role = lane bit
    #define SGL(g_, m_) { \
        const int bb = (t & (m_)) ? 1 : 0; \
        const float2 ca_ = bb ? G[g_][3] : G[g_][0]; \
        const float2 cb_ = bb ? G[g_][2] : G[g_][1]; \
        float2 p; \
        p.x = __shfl_xor(a0.x, m_); p.y = __shfl_xor(a0.y, m_); \
        a0 = cfma2(ca_, a0, cb_, p); \
        p.x = __shfl_xor(a1.x, m_); p.y = __shfl_xor(a1.y, m_); \
        a1 = cfma2(ca_, a1, cb_, p); }

    // complex gate on lane bit via DPP (masks 1,2)
    #define SGD(g_, CTRL_, m_) { \
        const int bb = (t & (m_)) ? 1 : 0; \
        const float2 ca_ = bb ? G[g_][3] : G[g_][0]; \
        const float2 cb_ = bb ? G[g_][2] : G[g_][1]; \
        float2 p = dpp_xor_f2<CTRL_>(a0); \
        a0 = cfma2(ca_, a0, cb_, p); \
        p = dpp_xor_f2<CTRL_>(a1); \
        a1 = cfma2(ca_, a1, cb_, p); }

    for (int l = 0; l < NL; ++l) {
        const int g0 = l*NQ;
        // phase A (L0: amp=(k<<10)|t): q0 reg; q5..q10 on lane bits 5..0
        CGK(g0+0)
        SGL(g0+5, 32) SGL(g0+6, 16) SGL(g0+7, 8) SGL(g0+8, 4)
        SGD(g0+9, 78, 2) SGD(g0+10, 177, 1)

        // X1 -> L1: amp[9:6]=t'[5:2], amp[5:2]=t'[9:6]
        lds[b0] = a0; lds[b0 ^ 1024] = a1;
        __syncthreads();
        a0 = lds[b1]; a1 = lds[b1 ^ 1024];

        // phase B: q1..q4 on amp bits 9..6 = lane bits 5..2
        SGL(g0+1, 32) SGL(g0+2, 16) SGL(g0+3, 8) SGL(g0+4, 4)

        // X2 write: exact same per-thread slots as X1 read -> no pre-barrier
        lds[b1] = a0; lds[b1 ^ 1024] = a1;
        __syncthreads();
        if (l < NL-1) {
            // perm-fold read back to L0: a[k] = state[g((k<<10)|t)]
            // k=1 offset: swzC(g(1<<10)) = swzC(1536) = 1544
            a0 = lds[b2]; a1 = lds[b2 ^ 1544];
            __syncthreads();   // slots differ from next layer's X1 write
        } else {
            // layer 5: no perm; natural-order cell write (amps 2t, 2t+1)
            const float2 lo = lds[bn], hi = lds[bn ^ 1];
            ws4[t] = make_float4(lo.x, lo.y, hi.x, hi.y);
        }
    }
    #undef CGK
    #undef SGL
    #undef SGD
}

// ========= kernel 2: cell-paired (float4) layout, 8192 blocks ================
// (byte-for-byte the proven R10 version)
__global__ __launch_bounds__(128, 4) void qnn_last_kernel(
    const float* __restrict__ X,      // (B, NQ)
    const float4* __restrict__ S5c,   // shared state, 1024 cells, natural order
    float4* __restrict__ out4)        // (B, 1024) cells
{
    __shared__ float4 ldsc[DIM/2];    // 1024 cells = 16 KB
    __shared__ float2 gc[NQ];
    const int b = blockIdx.x;
    const int t = threadIdx.x;        // 7 bits

    if (t < NQ) {
        const float tx = 0.5f * X[(size_t)b*NQ + t];
        gc[t] = make_float2(cosf(tx), sinf(tx));
    }

    // L0: a[2k+e] = amp s=(k<<8)|(t<<1)|e ; cell (k<<7)|t ; 1KB/wave loads
    v2f a[16];
    #pragma unroll
    for (int k = 0; k < 8; ++k) {
        const float4 v = S5c[(k<<7) | t];
        a[2*k]   = (v2f){v.x, v.y};
        a[2*k+1] = (v2f){v.z, v.w};
    }
    __syncthreads();   // bar1: gc ready

    // packed real RY on a-index bit rb_
    #define RG(q_, rb_) { \
        const float c = gc[q_].x, sn = gc[q_].y; \
        const v2f cc = {c, c}, sv = {sn, sn}; \
        _Pragma("unroll") \
        for (int j = 0; j < 16; ++j) if (!(j & (rb_))) { \
            const v2f a0 = a[j], a1 = a[j|(rb_)]; \
            a[j]       = cc*a0 - sv*a1; \
            a[j|(rb_)] = sv*a0 + cc*a1; \
        } }

    // o-domain conjugated RY: partner = lane-xor (DPP) of e-swapped reg
    #define CGD(q_, CTRL_, r_) { \
        const float c = gc[q_].x, sn = gc[q_].y; \
        const float sg = (r_) ? sn : -sn; \
        const v2f cc = {c, c}, sgv = {sg, sg}; \
        _Pragma("unroll") \
        for (int k = 0; k < 8; ++k) { \
            const v2f o0 = a[2*k], o1 = a[2*k+1]; \
            const v2f p0 = dpp_xor<CTRL_>(o1); \
            const v2f p1 = dpp_xor<CTRL_>(o0); \
            a[2*k]   = cc*o0 + sgv*p0; \
            a[2*k+1] = cc*o1 + sgv*p1; \
        } }

    // S1: reg amp-bits {10,9,8} = k, {0} = e
    RG(0, 8) RG(1, 4) RG(2, 2) RG(10, 1)

    // X1 write: cell (k<<7)|t
    #pragma unroll
    for (int k = 0; k < 8; ++k)
        ldsc[(k<<7) | t] = make_float4(a[2*k].x, a[2*k].y, a[2*k+1].x, a[2*k+1].y);
    __syncthreads();   // bar2
    // X1 read: s = (t[6:4]<<8)|(k<<5)|(t[3:1]<<2)|(t0<<1)|e ; cell = s>>1
    const int cR = ((t>>4)<<7) | (t & 15);
    #pragma unroll
    for (int k = 0; k < 8; ++k) {
        const float4 v = ldsc[cR | (k<<4)];
        a[2*k]   = (v2f){v.x, v.y};
        a[2*k+1] = (v2f){v.z, v.w};
    }
    // S2: reg amp-bits {7,6,5} = k
    RG(3, 8) RG(4, 4) RG(5, 2)
    __syncthreads();   // bar3: all X1 reads done before h-scattered writes

    // X2 write, perm-folded: amp s -> LDS slot h(s), so LDS[o] = V[g(o)].
    {
        const int sB    = (((t>>4)&7)<<8) | (((t>>1)&7)<<2) | ((t&1)<<1);
        const int cellB = hperm(sB) >> 1;
        const int pt    = __popc(t) & 1;
        #pragma unroll
        for (int k = 0; k < 8; ++k) {
            const int cell = cellB ^ (hperm(k<<5) >> 1);   // constexpr k-part
            const bool sw  = (pt ^ (__popc(k) & 1)) != 0;
            const v2f lo = sw ? a[2*k+1] : a[2*k];
            const v2f hi = sw ? a[2*k]   : a[2*k+1];
            ldsc[cell] = make_float4(lo.x, lo.y, hi.x, hi.y);
        }
    }
    __syncthreads();   // bar4

    // X2 read, linear: a[2k+e] = V[g(o)], o = (k<<8)|(t<<1)|e
    #pragma unroll
    for (int k = 0; k < 8; ++k) {
        const float4 v = ldsc[(k<<7) | t];
        a[2*k]   = (v2f){v.x, v.y};
        a[2*k+1] = (v2f){v.z, v.w};
    }

    // S3: q6..q9 conjugated through g -> lane-xor {15,7,3,1} + e-swap
    CGD(6, 0x140, ((t>>3) ^ (t>>4)) & 1)
    CGD(7, 0x141, ((t>>2) ^ (t>>3)) & 1)
    CGD(8, 27,    ((t>>1) ^ (t>>2)) & 1)
    CGD(9, 177,   ( t     ^ (t>>1)) & 1)

    // store: cell (k<<7)|t -> 1KB/wave contiguous bursts
    float4* o = out4 + (size_t)b * (DIM/2);
    #pragma unroll
    for (int k = 0; k < 8; ++k)
        o[(k<<7) | t] = make_float4(a[2*k].x, a[2*k].y, a[2*k+1].x, a[2*k+1].y);
    #undef RG
    #undef CGD
}

extern "C" void kernel_launch(void* const* d_in, const int* in_sizes, int n_in,
                              void* d_out, int out_size, void* d_ws, size_t ws_size,
                              hipStream_t stream) {
    const float* X = (const float*)d_in[0];   // (B, NQ) float32
    const float* P = (const float*)d_in[1];   // (NL, NQ, 3) float32
    float4* ws4 = (float4*)d_ws;              // 16 KB shared state, cell layout
    const int B = in_sizes[0] / NQ;           // 8192
    qnn_shared_kernel<<<1, 1024, 0, stream>>>(P, ws4);
    qnn_last_kernel<<<B, 128, 0, stream>>>(X, (const float4*)ws4, (float4*)d_out);
}